// Round 4
// baseline (145.079 us; speedup 1.0000x reference)
//
#include <hip/hip_runtime.h>
#include <math.h>

#define BB 16
#define NN 128
#define TT 512
#define CC 64
#define HH 64

typedef float f4v __attribute__((ext_vector_type(4)));

__device__ __forceinline__ float wsum64(float v) {
#pragma unroll
  for (int m = 1; m < 64; m <<= 1) v += __shfl_xor(v, m, 64);
  return v;
}

// K1: fused mean-over-N + projection + LayerNorm + L2.
// grid = BB*TT/4 = 2048 blocks, 256 threads. Block = 4 t-rows of one batch.
// LDS ~40KB -> 4 blocks/CU = 16 waves/CU (mean phase is BW-bound; enough).
__global__ __launch_bounds__(256) void mean_proj_kernel(
    const float* __restrict__ x, const float* __restrict__ Wq,
    const float* __restrict__ bq, const float* __restrict__ Wk,
    const float* __restrict__ bk, float* __restrict__ Qt,
    float* __restrict__ Kmat) {
  __shared__ float Wq_s[64 * 65];   // [c][h] transposed, pad 65
  __shared__ float Wk_s[64 * 65];
  __shared__ float red[4][4][64];   // [n-split][row][c]
  __shared__ float xm_s[4][64];     // mean tile
  __shared__ float qt_s[64 * 5];    // [h][row], pad 5

  const int tid = threadIdx.x;
  const int b = blockIdx.x >> 7;
  const int t0 = (blockIdx.x & 127) << 2;

  // Stage W transposed (32KB; L2-resident after first blocks).
  {
    const float4* wq4 = (const float4*)Wq;
    const float4* wk4 = (const float4*)Wk;
#pragma unroll
    for (int it = 0; it < 4; ++it) {
      int i4 = it * 256 + tid;            // 1024 float4 total
      float4 q = wq4[i4], k = wk4[i4];
      int h = i4 >> 4, c0 = (i4 & 15) * 4;
      Wq_s[(c0 + 0) * 65 + h] = q.x; Wq_s[(c0 + 1) * 65 + h] = q.y;
      Wq_s[(c0 + 2) * 65 + h] = q.z; Wq_s[(c0 + 3) * 65 + h] = q.w;
      Wk_s[(c0 + 0) * 65 + h] = k.x; Wk_s[(c0 + 1) * 65 + h] = k.y;
      Wk_s[(c0 + 2) * 65 + h] = k.z; Wk_s[(c0 + 3) * 65 + h] = k.w;
    }
  }

  // Mean over N: wave w covers n in [w*32, w*32+32). 1KB contiguous per instr.
  {
    const int w = tid >> 6;
    const int lane = tid & 63;
    const int j = lane >> 4;
    const int c4 = lane & 15;
    const f4v* xp = (const f4v*)x;
    size_t base4 = ((size_t)b * NN * TT + (size_t)(t0 + j)) * 16 + c4 +
                   (size_t)(w * 32) * (TT * 16);
    f4v s = {0.f, 0.f, 0.f, 0.f};
#pragma unroll 8
    for (int n = 0; n < 32; ++n) {
      s += xp[base4 + (size_t)n * (TT * 16)];
    }
    *(f4v*)&red[w][j][c4 * 4] = s;
  }
  __syncthreads();

  // Combine n-splits -> x_mean tile.
  {
    const int jj = tid >> 6, cc = tid & 63;
    xm_s[jj][cc] = (red[0][jj][cc] + red[1][jj][cc] + red[2][jj][cc] +
                    red[3][jj][cc]) * (1.f / 128.f);
  }
  __syncthreads();

  // Projection + LN + L2: wave rw = row, lane = h.
  const int rw = tid >> 6;
  const int h = tid & 63;
  float qa = bq[h], ka = bk[h];
#pragma unroll
  for (int c = 0; c < 64; ++c) {
    float xv = xm_s[rw][c];            // wave-uniform: broadcast
    qa = fmaf(xv, Wq_s[c * 65 + h], qa);
    ka = fmaf(xv, Wk_s[c * 65 + h], ka);
  }
  {
    const int t = t0 + rw;
    float mq = wsum64(qa) * (1.f / 64.f);
    float dq = qa - mq;
    float vq = wsum64(dq * dq) * (1.f / 64.f);
    float yq = dq / sqrtf(vq + 1e-5f);
    float nq = sqrtf(wsum64(yq * yq));
    yq = yq / fmaxf(nq, 1e-12f);
    qt_s[h * 5 + rw] = yq;

    float mk = wsum64(ka) * (1.f / 64.f);
    float dk = ka - mk;
    float vk = wsum64(dk * dk) * (1.f / 64.f);
    float yk = dk / sqrtf(vk + 1e-5f);
    float nk = sqrtf(wsum64(yk * yk));
    yk = yk / fmaxf(nk, 1e-12f);
    Kmat[((size_t)b * TT + t) * HH + h] = yk;   // coalesced
  }
  __syncthreads();

  // Qt (B,H,T): thread h (first wave) writes float4 of its 4 t's.
  if (tid < 64) {
    float4 o;
    o.x = qt_s[tid * 5 + 0]; o.y = qt_s[tid * 5 + 1];
    o.z = qt_s[tid * 5 + 2]; o.w = qt_s[tid * 5 + 3];
    *(float4*)&Qt[((size_t)b * HH + tid) * TT + t0] = o;
  }
}

// K2: fused logits (clip(QK^T)) + band softmax adjacency.
// grid = BB*32 = 512 blocks, 256 threads. Block = 16 rows x all 512 cols.
// K staged in 4 chunks of 128 rows ([128][68] = 34.8KB, conflict-free b128).
// Q read with block-uniform addresses (s_load path). nt stores (write-once).
__global__ __launch_bounds__(256) void logits_adj_kernel(
    const float* __restrict__ Qt, const float* __restrict__ Kmat,
    const int* __restrict__ bandp, float* __restrict__ logits,
    float* __restrict__ A) {
  __shared__ float Ks[128 * 68];
  __shared__ float bandv[16][17];   // clipped logits at |d|<=8
  __shared__ float finalA[16][17];
  __shared__ float off2s[16];

  const int tid = threadIdx.x;
  const int b = blockIdx.x >> 5;
  const int r0 = (blockIdx.x & 31) << 4;
  const int band = *bandp;
  const int colL = tid & 127;

  const float* qbase = Qt + (size_t)b * HH * TT + r0;  // block-uniform

  for (int chunk = 0; chunk < 4; ++chunk) {
    const int cbase = chunk << 7;
    // Stage K[cbase..cbase+127][0..63]: 32KB coalesced.
    {
      const float4* kg = (const float4*)(Kmat + ((size_t)b * TT + cbase) * HH);
#pragma unroll
      for (int it = 0; it < 8; ++it) {
        int g = it * 256 + tid;           // 2048 float4
        float4 v = kg[g];
        int row = g >> 4, h0 = (g & 15) * 4;
        float* d = &Ks[row * 68 + h0];
        d[0] = v.x; d[1] = v.y; d[2] = v.z; d[3] = v.w;
      }
    }
    __syncthreads();

    const int col = cbase + colL;
    const float* kr = &Ks[colL * 68];

    // roff is a literal (0 or 8) after inlining -> q addresses block-uniform.
    auto body = [&](int roff) {
      float acc[8] = {0.f, 0.f, 0.f, 0.f, 0.f, 0.f, 0.f, 0.f};
#pragma unroll
      for (int h4 = 0; h4 < 16; ++h4) {
        f4v k4 = *(const f4v*)&kr[h4 * 4];
#pragma unroll
        for (int j = 0; j < 4; ++j) {
          const float* qr = qbase + (size_t)(h4 * 4 + j) * TT + roff;
          float4 qlo = *(const float4*)qr;
          float4 qhi = *(const float4*)(qr + 4);
          float kk = k4[j];
          acc[0] = fmaf(qlo.x, kk, acc[0]);
          acc[1] = fmaf(qlo.y, kk, acc[1]);
          acc[2] = fmaf(qlo.z, kk, acc[2]);
          acc[3] = fmaf(qlo.w, kk, acc[3]);
          acc[4] = fmaf(qhi.x, kk, acc[4]);
          acc[5] = fmaf(qhi.y, kk, acc[5]);
          acc[6] = fmaf(qhi.z, kk, acc[6]);
          acc[7] = fmaf(qhi.w, kk, acc[7]);
        }
      }
#pragma unroll
      for (int r = 0; r < 8; ++r) {
        const int rl = roff + r;                  // row within tile
        float v = fminf(fmaxf(acc[r], -6.f), 6.f);
        __builtin_nontemporal_store(
            v, &logits[((size_t)b * TT + r0 + rl) * TT + col]);
        int d = col - (r0 + rl);
        if (d != 0 && d >= -band && d <= band && d >= -8 && d <= 8)
          bandv[rl][d + 8] = v;
      }
    };
    if (tid < 128) body(0); else body(8);
    __syncthreads();   // Ks reuse + bandv visibility
  }

  // Per-row band softmax scalars (16 rows -> 16 threads).
  if (tid < 16) {
    const int rg = r0 + tid;
    float mx = -3.0e38f;
    for (int jj = -band; jj <= band; ++jj) {
      if (jj == 0) continue;
      int ss = rg + jj;
      if (ss < 0 || ss >= TT || jj < -8 || jj > 8) continue;
      mx = fmaxf(mx, bandv[tid][jj + 8]);
    }
    float den = 0.f;
    int nb = 0;
    for (int jj = -band; jj <= band; ++jj) {
      if (jj == 0) continue;
      int ss = rg + jj;
      if (ss < 0 || ss >= TT || jj < -8 || jj > 8) continue;
      den += expf(bandv[tid][jj + 8] - mx);
      ++nb;
    }
    const float fl = 0.05f / (float)TT;
    const float offa = 0.95f * 1e-12f + fl;
    float bsum = 0.f;
    for (int jj = -band; jj <= band; ++jj) {
      if (jj == 0) continue;
      int ss = rg + jj;
      if (ss < 0 || ss >= TT || jj < -8 || jj > 8) continue;
      float p = expf(bandv[tid][jj + 8] - mx) / den;
      float a = fminf(0.95f * p + fl, 0.35f);
      bsum += a;
    }
    const float s1 = fmaxf(bsum + (float)(TT - nb) * offa, 1e-12f);
    const float off1 = offa / s1;
    float bsum1 = 0.f;
    for (int jj = -band; jj <= band; ++jj) {
      if (jj == 0) continue;
      int ss = rg + jj;
      if (ss < 0 || ss >= TT || jj < -8 || jj > 8) continue;
      float p = expf(bandv[tid][jj + 8] - mx) / den;
      float a = fminf(0.95f * p + fl, 0.35f);
      bsum1 += a / s1;
    }
    const float s2 = fmaxf(bsum1 + (float)(TT - nb) * off1, 1e-12f);
    const float off2 = off1 / s2;

    for (int e = 0; e < 17; ++e) finalA[tid][e] = off2;  // incl. diagonal
    for (int jj = -band; jj <= band; ++jj) {
      if (jj == 0) continue;
      int ss = rg + jj;
      if (ss < 0 || ss >= TT || jj < -8 || jj > 8) continue;
      float p = expf(bandv[tid][jj + 8] - mx) / den;
      float a = fminf(0.95f * p + fl, 0.35f);
      finalA[tid][jj + 8] = a / s1 / s2;
    }
    off2s[tid] = off2;
  }
  __syncthreads();

  // Write A: all cols, coalesced 256B per row per chunk.
  const int half = tid >> 7;
#pragma unroll
  for (int chunk = 0; chunk < 4; ++chunk) {
    const int col = (chunk << 7) + colL;
#pragma unroll
    for (int r = 0; r < 8; ++r) {
      const int rl = half * 8 + r;
      int d = col - (r0 + rl);
      float v = (d >= -band && d <= band && d >= -8 && d <= 8)
                    ? finalA[rl][d + 8]
                    : off2s[rl];
      __builtin_nontemporal_store(
          v, &A[((size_t)b * TT + r0 + rl) * TT + col]);
    }
  }
}

extern "C" void kernel_launch(void* const* d_in, const int* in_sizes, int n_in,
                              void* d_out, int out_size, void* d_ws, size_t ws_size,
                              hipStream_t stream) {
  (void)in_sizes; (void)n_in; (void)out_size; (void)ws_size;
  const float* x  = (const float*)d_in[0];
  const float* Wq = (const float*)d_in[1];
  const float* bq = (const float*)d_in[2];
  const float* Wk = (const float*)d_in[3];
  const float* bk = (const float*)d_in[4];
  const int* band = (const int*)d_in[5];

  float* A = (float*)d_out;                              // (B,T,T)
  float* logits = A + (size_t)BB * TT * TT;              // (B,T,T)
  float* Qt = (float*)d_ws;                              // (B,H,T)  2MB
  float* Kmat = Qt + (size_t)BB * HH * TT;               // (B,T,H)  2MB

  mean_proj_kernel<<<2048, 256, 0, stream>>>(x, Wq, bq, Wk, bk, Qt, Kmat);
  logits_adj_kernel<<<512, 256, 0, stream>>>(Qt, Kmat, band, logits, A);
}

// Round 5
// 104.623 us; speedup vs baseline: 1.3867x; 1.3867x over previous
//
#include <hip/hip_runtime.h>
#include <math.h>

#define BB 16
#define NN 128
#define TT 512
#define CC 64
#define HH 64

typedef float f4v __attribute__((ext_vector_type(4)));

__device__ __forceinline__ float wsum64(float v) {
#pragma unroll
  for (int m = 1; m < 64; m <<= 1) v += __shfl_xor(v, m, 64);
  return v;
}

// Kernel A1: x_mean = x.mean(axis=1) as a column-sum of a (N x T*C) matrix.
// grid = BB*32 = 512 blocks, 256 threads. Block = (b, 4KB column stripe).
// Register accumulators; every block-row-visit reads 4KB CONTIGUOUS (vs the
// old 1KB-chunk/128KB-stride pattern that sustained only ~3.2 TB/s).
__global__ __launch_bounds__(256) void mean_kernel(
    const float* __restrict__ x, float* __restrict__ xmean) {
  const int tid = threadIdx.x;
  const int b = blockIdx.x >> 5;            // batch
  const int s = blockIdx.x & 31;            // column stripe (1024 floats)

  const f4v* xp = (const f4v*)x;
  // row n: base (b*N + n)*T*C floats; stripe offset s*1024; thread float4.
  size_t base4 = ((size_t)b * NN) * (TT * CC / 4) + s * 256 + tid;
  const size_t rowstep = TT * CC / 4;       // 8192 float4 per n-row

  f4v acc = {0.f, 0.f, 0.f, 0.f};
#pragma unroll 8
  for (int n = 0; n < NN; ++n) {
    acc += xp[base4 + (size_t)n * rowstep];
  }
  acc *= (1.f / 128.f);
  ((f4v*)xmean)[(size_t)b * (TT * CC / 4) + s * 256 + tid] = acc;
}

// Kernel A2: projection + LayerNorm + L2 normalize from x_mean (2MB).
__global__ __launch_bounds__(256) void proj_kernel(
    const float* __restrict__ xmean, const float* __restrict__ Wq,
    const float* __restrict__ bq, const float* __restrict__ Wk,
    const float* __restrict__ bk, float* __restrict__ Qt,
    float* __restrict__ Kmat) {
  __shared__ float Wq_s[64 * 65];   // [c][h], pad 65 -> conflict-free
  __shared__ float Wk_s[64 * 65];
  __shared__ float xm_s[16 * 64];   // x_mean tile [row][c]
  __shared__ float qt_s[64 * 17];   // [h][row]

  const int tid = threadIdx.x;
  const int b = blockIdx.x >> 5;
  const int t0 = (blockIdx.x & 31) << 4;

#pragma unroll
  for (int it = 0; it < 16; ++it) {
    int i = it * 256 + tid;
    int h = i >> 6, c = i & 63;
    Wq_s[c * 65 + h] = Wq[i];
    Wk_s[c * 65 + h] = Wk[i];
  }
  ((float4*)xm_s)[tid] = ((const float4*)(xmean + ((size_t)b * TT + t0) * CC))[tid];
  __syncthreads();

  const int rw = tid >> 6;
  const int h = tid & 63;
  float qa[4], ka[4];
  const float bqv = bq[h], bkv = bk[h];
#pragma unroll
  for (int r = 0; r < 4; ++r) { qa[r] = bqv; ka[r] = bkv; }
#pragma unroll
  for (int c = 0; c < 64; ++c) {
    float wq = Wq_s[c * 65 + h];
    float wk = Wk_s[c * 65 + h];
#pragma unroll
    for (int r = 0; r < 4; ++r) {
      float xv = xm_s[(rw * 4 + r) * 64 + c];  // wave-uniform: broadcast
      qa[r] = fmaf(xv, wq, qa[r]);
      ka[r] = fmaf(xv, wk, ka[r]);
    }
  }

#pragma unroll
  for (int r = 0; r < 4; ++r) {
    const int t = t0 + rw * 4 + r;
    float mq = wsum64(qa[r]) * (1.f / 64.f);
    float dq = qa[r] - mq;
    float vq = wsum64(dq * dq) * (1.f / 64.f);
    float yq = dq / sqrtf(vq + 1e-5f);
    float nq = sqrtf(wsum64(yq * yq));
    yq = yq / fmaxf(nq, 1e-12f);
    qt_s[h * 17 + rw * 4 + r] = yq;

    float mk = wsum64(ka[r]) * (1.f / 64.f);
    float dk = ka[r] - mk;
    float vk = wsum64(dk * dk) * (1.f / 64.f);
    float yk = dk / sqrtf(vk + 1e-5f);
    float nk = sqrtf(wsum64(yk * yk));
    yk = yk / fmaxf(nk, 1e-12f);
    Kmat[((size_t)b * TT + t) * HH + h] = yk;
  }
  __syncthreads();

  {
    const int hh = tid >> 2, part = tid & 3;
    float4 o;
    o.x = qt_s[hh * 17 + part * 4 + 0];
    o.y = qt_s[hh * 17 + part * 4 + 1];
    o.z = qt_s[hh * 17 + part * 4 + 2];
    o.w = qt_s[hh * 17 + part * 4 + 3];
    *(float4*)&Qt[((size_t)b * HH + hh) * TT + t0 + part * 4] = o;
  }
}

// Kernel B: logits = clip(Q K^T, -6, 6). grid = 1024 blocks, 256 threads.
__global__ __launch_bounds__(256) void logits_kernel(
    const float* __restrict__ Qt, const float* __restrict__ Kmat,
    float* __restrict__ logits) {
  const int lane = threadIdx.x & 63;
  const int w = threadIdx.x >> 6;
  const int b = blockIdx.x >> 6;
  const int rem = blockIdx.x & 63;
  const int rg = rem >> 1;
  const int half = rem & 1;
  const int r0 = rg * 16;
  const int cg = half * 4 + w;
  const int scol = cg * 64 + lane;

  const float4* kp = (const float4*)(Kmat + ((size_t)b * TT + scol) * HH);
  float4 kv[16];
#pragma unroll
  for (int i = 0; i < 16; ++i) kv[i] = kp[i];

  float acc[16];
#pragma unroll
  for (int r = 0; r < 16; ++r) acc[r] = 0.f;

  const float* qtb = Qt + (size_t)b * HH * TT + r0;  // block-uniform
#pragma unroll
  for (int c4 = 0; c4 < 16; ++c4) {
    float4 k4 = kv[c4];
    const float* q0 = qtb + (size_t)(4 * c4 + 0) * TT;
    const float* q1 = qtb + (size_t)(4 * c4 + 1) * TT;
    const float* q2 = qtb + (size_t)(4 * c4 + 2) * TT;
    const float* q3 = qtb + (size_t)(4 * c4 + 3) * TT;
#pragma unroll
    for (int r = 0; r < 16; ++r) {
      acc[r] = fmaf(q0[r], k4.x, acc[r]);
      acc[r] = fmaf(q1[r], k4.y, acc[r]);
      acc[r] = fmaf(q2[r], k4.z, acc[r]);
      acc[r] = fmaf(q3[r], k4.w, acc[r]);
    }
  }

  float* lrow = logits + ((size_t)b * TT + r0) * TT + cg * 64 + lane;
#pragma unroll
  for (int r = 0; r < 16; ++r) {
    float v = fminf(fmaxf(acc[r], -6.f), 6.f);
    lrow[(size_t)r * TT] = v;
  }
}

// Kernel C: A from band logits. grid = B*T/4 = 2048 blocks, wave per row.
__global__ __launch_bounds__(256) void adj_kernel(
    const float* __restrict__ logits, const int* __restrict__ bandp,
    float* __restrict__ A) {
  const int w = threadIdx.x >> 6, lane = threadIdx.x & 63;
  const int row = blockIdx.x * 4 + w;   // row = b*T + t
  const int t = row & (TT - 1);
  const int band = *bandp;
  const float* lrow = logits + (size_t)row * TT;

  float mx = -3.0e38f;
  for (int jj = -band; jj <= band; ++jj) {
    if (jj == 0) continue;
    int ss = t + jj;
    if (ss < 0 || ss >= TT) continue;
    mx = fmaxf(mx, lrow[ss]);
  }
  float den = 0.f;
  int nb = 0;
  for (int jj = -band; jj <= band; ++jj) {
    if (jj == 0) continue;
    int ss = t + jj;
    if (ss < 0 || ss >= TT) continue;
    den += expf(lrow[ss] - mx);
    ++nb;
  }
  const float fl = 0.05f / (float)TT;
  const float offa = 0.95f * 1e-12f + fl;
  float bsum = 0.f;
  for (int jj = -band; jj <= band; ++jj) {
    if (jj == 0) continue;
    int ss = t + jj;
    if (ss < 0 || ss >= TT) continue;
    float p = expf(lrow[ss] - mx) / den;
    float a = fminf(0.95f * p + fl, 0.35f);
    bsum += a;
  }
  const float s1 = fmaxf(bsum + (float)(TT - nb) * offa, 1e-12f);
  const float off1 = offa / s1;
  float bsum1 = 0.f;
  for (int jj = -band; jj <= band; ++jj) {
    if (jj == 0) continue;
    int ss = t + jj;
    if (ss < 0 || ss >= TT) continue;
    float p = expf(lrow[ss] - mx) / den;
    float a = fminf(0.95f * p + fl, 0.35f);
    bsum1 += a / s1;
  }
  const float s2 = fmaxf(bsum1 + (float)(TT - nb) * off1, 1e-12f);
  const float off2 = off1 / s2;

  auto colval = [&](int ss) -> float {
    int d = ss - t;
    if (d != 0 && d >= -band && d <= band) {
      float p = expf(lrow[ss] - mx) / den;
      float a = fminf(0.95f * p + fl, 0.35f);
      return a / s1 / s2;
    }
    return off2;
  };

  float* arow = A + (size_t)row * TT + lane * 8;
  const int cb = lane * 8;
  float4 o0, o1;
  o0.x = colval(cb + 0); o0.y = colval(cb + 1);
  o0.z = colval(cb + 2); o0.w = colval(cb + 3);
  o1.x = colval(cb + 4); o1.y = colval(cb + 5);
  o1.z = colval(cb + 6); o1.w = colval(cb + 7);
  *(float4*)&arow[0] = o0;
  *(float4*)&arow[4] = o1;
}

extern "C" void kernel_launch(void* const* d_in, const int* in_sizes, int n_in,
                              void* d_out, int out_size, void* d_ws, size_t ws_size,
                              hipStream_t stream) {
  (void)in_sizes; (void)n_in; (void)out_size; (void)ws_size;
  const float* x  = (const float*)d_in[0];
  const float* Wq = (const float*)d_in[1];
  const float* bq = (const float*)d_in[2];
  const float* Wk = (const float*)d_in[3];
  const float* bk = (const float*)d_in[4];
  const int* band = (const int*)d_in[5];

  float* A = (float*)d_out;                              // (B,T,T)
  float* logits = A + (size_t)BB * TT * TT;              // (B,T,T)
  float* xmean = (float*)d_ws;                           // (B,T,C)  2MB
  float* Qt = xmean + (size_t)BB * TT * CC;              // (B,H,T)  2MB
  float* Kmat = Qt + (size_t)BB * HH * TT;               // (B,T,H)  2MB

  mean_kernel<<<512, 256, 0, stream>>>(x, xmean);
  proj_kernel<<<512, 256, 0, stream>>>(xmean, Wq, bq, Wk, bk, Qt, Kmat);
  logits_kernel<<<1024, 256, 0, stream>>>(Qt, Kmat, logits);
  adj_kernel<<<2048, 256, 0, stream>>>(logits, band, A);
}